// Round 4
// baseline (1522.181 us; speedup 1.0000x reference)
//
#include <hip/hip_runtime.h>
#include <math.h>

// Viterbi posterior_mode, bitwise-faithful to the f32 reference:
//   alpha_{t}[j] = max_i(alpha_{t-1}[i] + LT[i][j]) + e_t   (f32, RTNE, first-win argmax)
// K1: sequential alpha-only, ALL-VALU butterfly (DPP + permlane_swap, no DS pipe).
// K2: parallel per-chunk recompute with backpointers + fused map composition. K3/K4 backtrack.

#define BB 256
#define TT 8192
#define SS 32
#define LCH 256
#define NCH 32

static constexpr size_t OFF_LTC  = 0;                                    // 32*32 f32 col-major
static constexpr size_t OFF_LI   = 4096;                                 // 32 f32
static constexpr size_t OFF_LTR  = 4224;                                 // 32*32 f32 row-major
static constexpr size_t OFF_BND  = 8448;                                 // NCH*BB*SS f32
static constexpr size_t OFF_LAST = OFF_BND + (size_t)NCH * BB * SS * 4;  // BB i32
static constexpr size_t OFF_H    = OFF_LAST + (size_t)BB * 4;            // NCH*BB*SS u8
static constexpr size_t OFF_SE   = OFF_H + (size_t)NCH * BB * SS;        // NCH*BB u8
static constexpr size_t OFF_BP   = (OFF_SE + (size_t)NCH * BB + 4095) & ~(size_t)4095; // TT*BB*SS u8

static __device__ __forceinline__ float rlane(float v, int i) {
  return __int_as_float(__builtin_amdgcn_readlane(__float_as_int(v), i));
}
// e = (-0.5 * x) * x - HALF_LOG_2PI, exactly as the reference (no FMA contraction)
static __device__ __forceinline__ float emis_f(float x) {
  return __fsub_rn(__fmul_rn(__fmul_rn(-0.5f, x), x), 0.9189385332046727f);
}

// ---- K0: logs (double route -> correctly rounded f32) ----
__global__ void k_prep(const float* __restrict__ hmm, float* __restrict__ ltc,
                       float* __restrict__ li, float* __restrict__ ltr) {
  int tid = threadIdx.x;
  for (int k = tid; k < SS * SS; k += 256) {
    int i = k >> 5, j = k & 31;
    float v = (float)log((double)hmm[i * SS + j]);
    ltc[j * SS + i] = v;   // column-major (k_chunks)
    ltr[i * SS + j] = v;   // row-major (k_fwd)
  }
  if (tid < SS) li[tid] = (float)log((double)hmm[tid]);
}

// ---- K1: all-VALU butterfly step ----
// DPP move of src (compile-time ctrl), fusion-friendly form (old=0, bound_ctrl=1).
template<int CTRL>
static __device__ __forceinline__ float dppmov(float src) {
  return __int_as_float(
      __builtin_amdgcn_update_dpp(0, __float_as_int(src), CTRL, 0xf, 0xf, true));
}
template<int CTRL>
static __device__ __forceinline__ float dppmax(float acc, float src) {
  return fmaxf(acc, dppmov<CTRL>(src));
}
// max over {v[l], v[l^16]} — immune to permlane row-swap semantics:
// (r0,r1) = permlane16_swap(v,v) yields per-lane {self, partner} in some order.
static __device__ __forceinline__ float plmax16(float v) {
  auto r = __builtin_amdgcn_permlane16_swap(__float_as_uint(v), __float_as_uint(v),
                                            false, false);
  return fmaxf(fmaxf(v, __uint_as_float(r[0])), __uint_as_float(r[1]));
}
static __device__ __forceinline__ float plmax32(float v) {
  auto r = __builtin_amdgcn_permlane32_swap(__float_as_uint(v), __float_as_uint(v),
                                            false, false);
  return fmaxf(fmaxf(v, __uint_as_float(r[0])), __uint_as_float(r[1]));
}

// One Viterbi value-step. lane l holds a = alpha_{sig(l)}; lt[r] = LT[sig(l)][j(l,r)].
// Butterfly masks: st1=2 (quad 0x4E), st2=7 (half_mirror 0x141), st3=8 (ror8 0x128),
// st4=16 (permlane16), st5=32 (permlane32). Output select by lane bits 4,5.
static __device__ __forceinline__ float fstep(float a, const float* lt, float e,
                                              bool b4, bool b5) {
  float p[16];
#pragma unroll
  for (int r = 0; r < 16; ++r) p[r] = __fadd_rn(a, lt[r]);
#pragma unroll
  for (int s = 0; s < 8; ++s) p[s] = dppmax<0x4E>(p[s], p[s ^ 8]);
#pragma unroll
  for (int s = 0; s < 4; ++s) p[s] = dppmax<0x141>(p[s], p[s ^ 4]);
#pragma unroll
  for (int s = 0; s < 2; ++s) p[s] = dppmax<0x128>(p[s], p[s ^ 2]);
  p[0] = plmax16(p[0]);
  p[1] = plmax16(p[1]);
  p[0] = plmax32(p[0]);
  p[1] = plmax32(p[1]);
  float n0 = dppmov<0xB1>(p[0]);   // quad_perm [1,0,3,2] = xor1 neighbor
  float n1 = dppmov<0xB1>(p[1]);
  float lo = b5 ? p[1] : p[0];
  float hi = b5 ? n1 : n0;
  float v  = b4 ? hi : lo;
  return __fadd_rn(v, e);
}

__global__ __launch_bounds__(64) void k_fwd(const float* __restrict__ x,
                                            const float* __restrict__ ltr,
                                            const float* __restrict__ li,
                                            float* __restrict__ bnd,
                                            int* __restrict__ last) {
  const int b = blockIdx.x, tid = threadIdx.x;
  const int l = tid;
  const int f0 = __popc(l & 5) & 1;
  const int f1 = __popc(l & 6) & 1;
  const int f2 = (l >> 2) & 1;
  const int f3 = (l >> 3) & 1;
  const bool b4 = (l >> 4) & 1;
  const bool b5 = (l >> 5) & 1;
  // column of p[r]: j = (f0<<4)|((r3^f1)<<3)|((r2^f2)<<2)|((r1^f3)<<1)|r0
  const int A = (f0 << 4) | (f1 << 3) | (f2 << 2) | (f3 << 1);      // col of p[0]
  const int sig = ((f0 ^ (int)b4) << 4) | (f1 << 3) | (f2 << 2) | (f3 << 1) | (int)b5;
  float lt[16];
#pragma unroll
  for (int r = 0; r < 16; ++r) {
    int j = (f0 << 4) | ((((r >> 3) & 1) ^ f1) << 3) | ((((r >> 2) & 1) ^ f2) << 2) |
            ((((r >> 1) & 1) ^ f3) << 1) | (r & 1);
    lt[r] = ltr[(size_t)sig * SS + j];
  }
  const float* xb = x + (size_t)b * TT;
  const int m = tid & 31;
  float xcur = xb[m];
  float ev = emis_f(xcur);
  float xnxt = xb[32 + m];
  float a = __fadd_rn(li[sig], rlane(ev, 0));       // alpha_0
  bnd[(size_t)b * SS + sig] = a;                    // chunk-0 boundary (dup writes ok)
#pragma unroll
  for (int k = 1; k < 32; ++k) a = fstep(a, lt, rlane(ev, k), b4, b5);
  for (int t0 = 32; t0 < TT; t0 += 32) {
    ev = emis_f(xnxt);
    if (t0 + 32 < TT) xnxt = xb[t0 + 32 + m];
    a = fstep(a, lt, rlane(ev, 0), b4, b5);         // t = t0
    if ((t0 & 255) == 0)
      bnd[((size_t)(t0 >> 8) * BB + b) * SS + sig] = a;
#pragma unroll
    for (int k = 1; k < 32; ++k) a = fstep(a, lt, rlane(ev, k), b4, b5);
  }
  // last[b] = argmax_j alpha, first (lowest state index) wins
  float mx = a;
#pragma unroll
  for (int o = 1; o < 64; o <<= 1) mx = fmaxf(mx, __shfl_xor(mx, o, 64));
  int v = (a == mx) ? sig : 63;
#pragma unroll
  for (int o = 1; o < 64; o <<= 1) { int u = __shfl_xor(v, o, 64); v = u < v ? u : v; }
  if (tid == 0) last[b] = v;
}

// ---- K2: parallel chunk recompute: backpointers + fused map composition ----
__global__ __launch_bounds__(256) void k_chunks(const float* __restrict__ x,
                                                const float* __restrict__ ltc,
                                                const float* __restrict__ bnd,
                                                unsigned char* __restrict__ bp,
                                                unsigned char* __restrict__ H) {
  __shared__ float alf[8][32];
  __shared__ float els[8][32];
  const int tid = threadIdx.x;
  const int w = tid >> 5, j = tid & 31;
  const int c = blockIdx.x >> 5;
  const int b = ((blockIdx.x & 31) << 3) + w;
  const int tlo = c * LCH;
  const int thi = (tlo + LCH < TT - 1) ? (tlo + LCH) : (TT - 1);
  float lt[32];
  {
    const float4* ltv = (const float4*)(ltc + (size_t)j * SS);
#pragma unroll
    for (int q = 0; q < 8; ++q) {
      float4 v = ltv[q];
      lt[4 * q + 0] = v.x; lt[4 * q + 1] = v.y; lt[4 * q + 2] = v.z; lt[4 * q + 3] = v.w;
    }
  }
  float alpha = bnd[((size_t)c * BB + b) * SS + j];
  int comp = j;  // composed map: end-state -> state at tlo
  const float* xb = x + (size_t)b * TT;

  for (int tg = tlo + 1; tg <= thi; tg += 32) {
    const int kn = (32 < thi - tg + 1) ? 32 : (thi - tg + 1);
    float xv = (j < kn) ? xb[tg + j] : 0.0f;
    els[w][j] = emis_f(xv);   // half-wave private, lockstep -> no barrier
    for (int k = 0; k < kn; ++k) {
      const int t = tg + k;
      alf[w][j] = alpha;
      float sc[32];
      const float4* ap = (const float4*)alf[w];
#pragma unroll
      for (int q = 0; q < 8; ++q) {
        float4 v = ap[q];
        sc[4 * q + 0] = __fadd_rn(v.x, lt[4 * q + 0]);
        sc[4 * q + 1] = __fadd_rn(v.y, lt[4 * q + 1]);
        sc[4 * q + 2] = __fadd_rn(v.z, lt[4 * q + 2]);
        sc[4 * q + 3] = __fadd_rn(v.w, lt[4 * q + 3]);
      }
      // max value (order-free, exact), then first-win index via descending eq-scan
      float mm = sc[0];
#pragma unroll
      for (int i = 1; i < 32; ++i) mm = fmaxf(mm, sc[i]);
      int idx = 31;
#pragma unroll
      for (int i = 30; i >= 0; --i) idx = (sc[i] == mm) ? i : idx;
      alpha = __fadd_rn(mm, els[w][k]);
      bp[(size_t)t * (BB * SS) + (size_t)b * SS + j] = (unsigned char)idx;
      comp = __shfl(comp, idx, 32);  // comp_new[j] = comp_old[bp_t[j]]
    }
  }
  H[((size_t)c * BB + b) * SS + j] = (unsigned char)comp;
}

// ---- K3: boundary backtrack over composed chunk maps (+ states[b][0]) ----
__global__ void k_bound(const int* __restrict__ last, const unsigned char* __restrict__ H,
                        unsigned char* __restrict__ se, int* __restrict__ out) {
  int b = threadIdx.x;  // one block of 256
  int s = last[b];
  for (int c = NCH - 1; c >= 0; --c) {
    se[(size_t)c * BB + b] = (unsigned char)s;      // state at t_hi(c)
    s = H[((size_t)c * BB + b) * SS + s];           // -> state at 256c
  }
  out[(size_t)b * TT] = s;                          // states[b][0]
}

// ---- K4: fill per-chunk paths from bp (LDS-staged walk) ----
__global__ __launch_bounds__(256) void k_fill(const unsigned char* __restrict__ bp,
                                              const unsigned char* __restrict__ se,
                                              int* __restrict__ out) {
  __shared__ unsigned char lbp[8][LCH * SS];  // 64 KiB
  const int tid = threadIdx.x;
  const int w = tid >> 5, j = tid & 31;
  const int c = blockIdx.x >> 5;
  const int b = ((blockIdx.x & 31) << 3) + w;
  const int tlo = c * LCH;
  const int thi = (tlo + LCH < TT - 1) ? (tlo + LCH) : (TT - 1);
  const int n = thi - tlo;
  for (int k = 0; k < n; ++k)
    lbp[w][k * SS + j] = bp[(size_t)(tlo + 1 + k) * (BB * SS) + (size_t)b * SS + j];
  __builtin_amdgcn_wave_barrier();
  if (j == 0) {
    int s = se[(size_t)c * BB + b];                 // state at t_hi
    int* ob = out + (size_t)b * TT;
    for (int k = n - 1; k >= 0; --k) {
      ob[tlo + 1 + k] = s;
      s = lbp[w][k * SS + s];
    }
  }
}

extern "C" void kernel_launch(void* const* d_in, const int* in_sizes, int n_in,
                              void* d_out, int out_size, void* d_ws, size_t ws_size,
                              hipStream_t stream) {
  const float* x   = (const float*)d_in[0];   // inputs [B,T] f32
  const float* hmm = (const float*)d_in[1];   // hmm_params [U,S,S] f32 (only [0] used)
  int* out = (int*)d_out;                     // states [B,T] int32
  char* ws = (char*)d_ws;

  float* ltc = (float*)(ws + OFF_LTC);
  float* li  = (float*)(ws + OFF_LI);
  float* ltr = (float*)(ws + OFF_LTR);
  float* bnd = (float*)(ws + OFF_BND);
  int*   lst = (int*)(ws + OFF_LAST);
  unsigned char* H  = (unsigned char*)(ws + OFF_H);
  unsigned char* se = (unsigned char*)(ws + OFF_SE);
  unsigned char* bp = (unsigned char*)(ws + OFF_BP);

  k_prep  <<<1,    256, 0, stream>>>(hmm, ltc, li, ltr);
  k_fwd   <<<BB,   64,  0, stream>>>(x, ltr, li, bnd, lst);
  k_chunks<<<1024, 256, 0, stream>>>(x, ltc, bnd, bp, H);
  k_bound <<<1,    256, 0, stream>>>(lst, H, se, out);
  k_fill  <<<1024, 256, 0, stream>>>(bp, se, out);
}

// Round 6
// 1309.168 us; speedup vs baseline: 1.1627x; 1.1627x over previous
//
#include <hip/hip_runtime.h>
#include <math.h>

// Viterbi posterior_mode, bitwise-faithful to the f32 reference:
//   alpha_{t}[j] = max_i(alpha_{t-1}[i] + LT[i][j]) + e_t   (f32, RTNE, first-win argmax)
// K1: sequential alpha-only; hot core = hand-scheduled inline-asm DPP butterfly
//     (16 v_add + 14 v_max_f32_dpp, 1 inst/op, hazard-safe spacing), permlane
//     crossings + select via proven builtins, e-values hoisted to SGPRs.
// K2: parallel per-chunk recompute with backpointers + fused map composition. K3/K4 backtrack.

#define BB 256
#define TT 8192
#define SS 32
#define LCH 256
#define NCH 32

static constexpr size_t OFF_LTC  = 0;                                    // 32*32 f32 col-major
static constexpr size_t OFF_LI   = 4096;                                 // 32 f32
static constexpr size_t OFF_LTR  = 4224;                                 // 32*32 f32 row-major
static constexpr size_t OFF_BND  = 8448;                                 // NCH*BB*SS f32
static constexpr size_t OFF_LAST = OFF_BND + (size_t)NCH * BB * SS * 4;  // BB i32
static constexpr size_t OFF_H    = OFF_LAST + (size_t)BB * 4;            // NCH*BB*SS u8
static constexpr size_t OFF_SE   = OFF_H + (size_t)NCH * BB * SS;        // NCH*BB u8
static constexpr size_t OFF_BP   = (OFF_SE + (size_t)NCH * BB + 4095) & ~(size_t)4095; // TT*BB*SS u8

static __device__ __forceinline__ float rlane(float v, int i) {
  return __int_as_float(__builtin_amdgcn_readlane(__float_as_int(v), i));
}
// e = (-0.5 * x) * x - HALF_LOG_2PI, exactly as the reference (no FMA contraction)
static __device__ __forceinline__ float emis_f(float x) {
  return __fsub_rn(__fmul_rn(__fmul_rn(-0.5f, x), x), 0.9189385332046727f);
}

// ---- K0: logs (double route -> correctly rounded f32) ----
__global__ void k_prep(const float* __restrict__ hmm, float* __restrict__ ltc,
                       float* __restrict__ li, float* __restrict__ ltr) {
  int tid = threadIdx.x;
  for (int k = tid; k < SS * SS; k += 256) {
    int i = k >> 5, j = k & 31;
    float v = (float)log((double)hmm[i * SS + j]);
    ltc[j * SS + i] = v;   // column-major (k_chunks)
    ltr[i * SS + j] = v;   // row-major (k_fwd)
  }
  if (tid < SS) li[tid] = (float)log((double)hmm[tid]);
}

// DPP move of src (compile-time ctrl) — for the select path only.
template<int CTRL>
static __device__ __forceinline__ float dppmov(float src) {
  return __int_as_float(
      __builtin_amdgcn_update_dpp(0, __float_as_int(src), CTRL, 0xf, 0xf, true));
}
// max over {v[l], v[l^16]} / {v[l], v[l^32]} — immune to permlane row-swap semantics:
// swap(v,v) yields per-lane the multiset {self, partner}; max over it is exact.
static __device__ __forceinline__ float plmax16(float v) {
  auto r = __builtin_amdgcn_permlane16_swap(__float_as_uint(v), __float_as_uint(v),
                                            false, false);
  return fmaxf(fmaxf(v, __uint_as_float(r[0])), __uint_as_float(r[1]));
}
static __device__ __forceinline__ float plmax32(float v) {
  auto r = __builtin_amdgcn_permlane32_swap(__float_as_uint(v), __float_as_uint(v),
                                            false, false);
  return fmaxf(fmaxf(v, __uint_as_float(r[0])), __uint_as_float(r[1]));
}

// Hot core: p[r] = a + lt[r] (r=0..15), then 3 butterfly levels (xor2 quad_perm,
// xor7 row_half_mirror, xor8 row_ror:8). p0 -> P0, p1 -> P1.
// Scheduling: every DPP read is >=4 instructions after its source's last write.
static __device__ __forceinline__ void fcore(float a, const float* lt,
                                             float& P0, float& P1) {
  asm("v_add_f32 v48, %[A], %[l8]\n\t"
      "v_add_f32 v49, %[A], %[l9]\n\t"
      "v_add_f32 v50, %[A], %[l10]\n\t"
      "v_add_f32 v51, %[A], %[l11]\n\t"
      "v_add_f32 v52, %[A], %[l12]\n\t"
      "v_add_f32 v53, %[A], %[l13]\n\t"
      "v_add_f32 v54, %[A], %[l14]\n\t"
      "v_add_f32 v55, %[A], %[l15]\n\t"
      "v_add_f32 %[P0], %[A], %[l0]\n\t"
      "v_add_f32 %[P1], %[A], %[l1]\n\t"
      "v_add_f32 v42, %[A], %[l2]\n\t"
      "v_add_f32 v43, %[A], %[l3]\n\t"
      "v_add_f32 v44, %[A], %[l4]\n\t"
      "v_add_f32 v45, %[A], %[l5]\n\t"
      "v_add_f32 v46, %[A], %[l6]\n\t"
      "v_add_f32 v47, %[A], %[l7]\n\t"
      // L1: p[s] <- max(dpp_xor2(p[s+8]), p[s]); order s=4,5,6,7,0,1,2,3
      "v_max_f32_dpp v44, v52, v44 quad_perm:[2,3,0,1] row_mask:0xf bank_mask:0xf\n\t"
      "v_max_f32_dpp v45, v53, v45 quad_perm:[2,3,0,1] row_mask:0xf bank_mask:0xf\n\t"
      "v_max_f32_dpp v46, v54, v46 quad_perm:[2,3,0,1] row_mask:0xf bank_mask:0xf\n\t"
      "v_max_f32_dpp v47, v55, v47 quad_perm:[2,3,0,1] row_mask:0xf bank_mask:0xf\n\t"
      "v_max_f32_dpp %[P0], v48, %[P0] quad_perm:[2,3,0,1] row_mask:0xf bank_mask:0xf\n\t"
      "v_max_f32_dpp %[P1], v49, %[P1] quad_perm:[2,3,0,1] row_mask:0xf bank_mask:0xf\n\t"
      "v_max_f32_dpp v42, v50, v42 quad_perm:[2,3,0,1] row_mask:0xf bank_mask:0xf\n\t"
      "v_max_f32_dpp v43, v51, v43 quad_perm:[2,3,0,1] row_mask:0xf bank_mask:0xf\n\t"
      // L2: p[s] <- max(dpp_xor7(p[s+4]), p[s]); order s=2,3,0,1
      "v_max_f32_dpp v42, v46, v42 row_half_mirror row_mask:0xf bank_mask:0xf\n\t"
      "v_max_f32_dpp v43, v47, v43 row_half_mirror row_mask:0xf bank_mask:0xf\n\t"
      "v_max_f32_dpp %[P0], v44, %[P0] row_half_mirror row_mask:0xf bank_mask:0xf\n\t"
      "v_max_f32_dpp %[P1], v45, %[P1] row_half_mirror row_mask:0xf bank_mask:0xf\n\t"
      // L3: p0 <- max(dpp_xor8(p2), p0); p1 <- max(dpp_xor8(p3), p1)
      "v_max_f32_dpp %[P0], v42, %[P0] row_ror:8 row_mask:0xf bank_mask:0xf\n\t"
      "v_max_f32_dpp %[P1], v43, %[P1] row_ror:8 row_mask:0xf bank_mask:0xf"
      : [P0] "=&v"(P0), [P1] "=&v"(P1)
      : [A] "v"(a), [l0] "v"(lt[0]), [l1] "v"(lt[1]), [l2] "v"(lt[2]),
        [l3] "v"(lt[3]), [l4] "v"(lt[4]), [l5] "v"(lt[5]), [l6] "v"(lt[6]),
        [l7] "v"(lt[7]), [l8] "v"(lt[8]), [l9] "v"(lt[9]), [l10] "v"(lt[10]),
        [l11] "v"(lt[11]), [l12] "v"(lt[12]), [l13] "v"(lt[13]), [l14] "v"(lt[14]),
        [l15] "v"(lt[15])
      : "v42", "v43", "v44", "v45", "v46", "v47", "v48", "v49", "v50", "v51",
        "v52", "v53", "v54", "v55");
}

// One Viterbi value-step (dataflow identical to the round-4 passing kernel).
static __device__ __forceinline__ float fstep(float a, const float* lt, float e,
                                              bool b4, bool b5) {
  float P0, P1;
  fcore(a, lt, P0, P1);
  float p0 = plmax16(P0);
  float p1 = plmax16(P1);
  p0 = plmax32(p0);
  p1 = plmax32(p1);
  float n0 = dppmov<0xB1>(p0);   // quad_perm [1,0,3,2] = xor1 neighbor
  float n1 = dppmov<0xB1>(p1);
  float lo = b5 ? p1 : p0;
  float hi = b5 ? n1 : n0;
  float v  = b4 ? hi : lo;
  return __fadd_rn(v, e);
}

__global__ __launch_bounds__(64) void k_fwd(const float* __restrict__ x,
                                            const float* __restrict__ ltr,
                                            const float* __restrict__ li,
                                            float* __restrict__ bnd,
                                            int* __restrict__ last) {
  const int b = blockIdx.x, tid = threadIdx.x;
  const int l = tid;
  const int f0 = __popc(l & 5) & 1;
  const int f1 = __popc(l & 6) & 1;
  const int f2 = (l >> 2) & 1;
  const int f3 = (l >> 3) & 1;
  const bool b4 = (l >> 4) & 1;
  const bool b5 = (l >> 5) & 1;
  const int sig = ((f0 ^ (int)b4) << 4) | (f1 << 3) | (f2 << 2) | (f3 << 1) | (int)b5;
  float lt[16];
#pragma unroll
  for (int r = 0; r < 16; ++r) {
    int j = (f0 << 4) | ((((r >> 3) & 1) ^ f1) << 3) | ((((r >> 2) & 1) ^ f2) << 2) |
            ((((r >> 1) & 1) ^ f3) << 1) | (r & 1);
    lt[r] = ltr[(size_t)sig * SS + j];
  }
  const float* xb = x + (size_t)b * TT;
  const int m = tid & 31;
  float xcur = xb[m];
  float ev = emis_f(xcur);
  float xnxt = xb[32 + m];
  float es[32];
#pragma unroll
  for (int k = 0; k < 32; ++k) es[k] = rlane(ev, k);   // uniform -> SGPRs
  float a = __fadd_rn(li[sig], es[0]);                 // alpha_0
  bnd[(size_t)b * SS + sig] = a;                       // chunk-0 boundary (dup writes ok)
#pragma unroll
  for (int k = 1; k < 32; ++k) a = fstep(a, lt, es[k], b4, b5);
  for (int t0 = 32; t0 < TT; t0 += 32) {
    ev = emis_f(xnxt);
    if (t0 + 32 < TT) xnxt = xb[t0 + 32 + m];
#pragma unroll
    for (int k = 0; k < 32; ++k) es[k] = rlane(ev, k);
    a = fstep(a, lt, es[0], b4, b5);                   // t = t0
    if ((t0 & 255) == 0)
      bnd[((size_t)(t0 >> 8) * BB + b) * SS + sig] = a;
#pragma unroll
    for (int k = 1; k < 32; ++k) a = fstep(a, lt, es[k], b4, b5);
  }
  // last[b] = argmax_j alpha, first (lowest state index) wins
  float mx = a;
#pragma unroll
  for (int o = 1; o < 64; o <<= 1) mx = fmaxf(mx, __shfl_xor(mx, o, 64));
  int v = (a == mx) ? sig : 63;
#pragma unroll
  for (int o = 1; o < 64; o <<= 1) { int u = __shfl_xor(v, o, 64); v = u < v ? u : v; }
  if (tid == 0) last[b] = v;
}

// ---- K2: parallel chunk recompute: backpointers + fused map composition ----
__global__ __launch_bounds__(256) void k_chunks(const float* __restrict__ x,
                                                const float* __restrict__ ltc,
                                                const float* __restrict__ bnd,
                                                unsigned char* __restrict__ bp,
                                                unsigned char* __restrict__ H) {
  __shared__ float alf[8][32];
  __shared__ float els[8][32];
  const int tid = threadIdx.x;
  const int w = tid >> 5, j = tid & 31;
  const int c = blockIdx.x >> 5;
  const int b = ((blockIdx.x & 31) << 3) + w;
  const int tlo = c * LCH;
  const int thi = (tlo + LCH < TT - 1) ? (tlo + LCH) : (TT - 1);
  float lt[32];
  {
    const float4* ltv = (const float4*)(ltc + (size_t)j * SS);
#pragma unroll
    for (int q = 0; q < 8; ++q) {
      float4 v = ltv[q];
      lt[4 * q + 0] = v.x; lt[4 * q + 1] = v.y; lt[4 * q + 2] = v.z; lt[4 * q + 3] = v.w;
    }
  }
  float alpha = bnd[((size_t)c * BB + b) * SS + j];
  int comp = j;  // composed map: end-state -> state at tlo
  const float* xb = x + (size_t)b * TT;

  for (int tg = tlo + 1; tg <= thi; tg += 32) {
    const int kn = (32 < thi - tg + 1) ? 32 : (thi - tg + 1);
    float xv = (j < kn) ? xb[tg + j] : 0.0f;
    els[w][j] = emis_f(xv);   // half-wave private, lockstep -> no barrier
    for (int k = 0; k < kn; ++k) {
      const int t = tg + k;
      alf[w][j] = alpha;
      float sc[32];
      const float4* ap = (const float4*)alf[w];
#pragma unroll
      for (int q = 0; q < 8; ++q) {
        float4 v = ap[q];
        sc[4 * q + 0] = __fadd_rn(v.x, lt[4 * q + 0]);
        sc[4 * q + 1] = __fadd_rn(v.y, lt[4 * q + 1]);
        sc[4 * q + 2] = __fadd_rn(v.z, lt[4 * q + 2]);
        sc[4 * q + 3] = __fadd_rn(v.w, lt[4 * q + 3]);
      }
      // max value (order-free, exact), then first-win index via descending eq-scan
      float mm = sc[0];
#pragma unroll
      for (int i = 1; i < 32; ++i) mm = fmaxf(mm, sc[i]);
      int idx = 31;
#pragma unroll
      for (int i = 30; i >= 0; --i) idx = (sc[i] == mm) ? i : idx;
      alpha = __fadd_rn(mm, els[w][k]);
      bp[(size_t)t * (BB * SS) + (size_t)b * SS + j] = (unsigned char)idx;
      comp = __shfl(comp, idx, 32);  // comp_new[j] = comp_old[bp_t[j]]
    }
  }
  H[((size_t)c * BB + b) * SS + j] = (unsigned char)comp;
}

// ---- K3: boundary backtrack over composed chunk maps (+ states[b][0]) ----
__global__ void k_bound(const int* __restrict__ last, const unsigned char* __restrict__ H,
                        unsigned char* __restrict__ se, int* __restrict__ out) {
  int b = threadIdx.x;  // one block of 256
  int s = last[b];
  for (int c = NCH - 1; c >= 0; --c) {
    se[(size_t)c * BB + b] = (unsigned char)s;      // state at t_hi(c)
    s = H[((size_t)c * BB + b) * SS + s];           // -> state at 256c
  }
  out[(size_t)b * TT] = s;                          // states[b][0]
}

// ---- K4: fill per-chunk paths from bp (LDS-staged walk) ----
__global__ __launch_bounds__(256) void k_fill(const unsigned char* __restrict__ bp,
                                              const unsigned char* __restrict__ se,
                                              int* __restrict__ out) {
  __shared__ unsigned char lbp[8][LCH * SS];  // 64 KiB
  const int tid = threadIdx.x;
  const int w = tid >> 5, j = tid & 31;
  const int c = blockIdx.x >> 5;
  const int b = ((blockIdx.x & 31) << 3) + w;
  const int tlo = c * LCH;
  const int thi = (tlo + LCH < TT - 1) ? (tlo + LCH) : (TT - 1);
  const int n = thi - tlo;
  for (int k = 0; k < n; ++k)
    lbp[w][k * SS + j] = bp[(size_t)(tlo + 1 + k) * (BB * SS) + (size_t)b * SS + j];
  __builtin_amdgcn_wave_barrier();
  if (j == 0) {
    int s = se[(size_t)c * BB + b];                 // state at t_hi
    int* ob = out + (size_t)b * TT;
    for (int k = n - 1; k >= 0; --k) {
      ob[tlo + 1 + k] = s;
      s = lbp[w][k * SS + s];
    }
  }
}

extern "C" void kernel_launch(void* const* d_in, const int* in_sizes, int n_in,
                              void* d_out, int out_size, void* d_ws, size_t ws_size,
                              hipStream_t stream) {
  const float* x   = (const float*)d_in[0];   // inputs [B,T] f32
  const float* hmm = (const float*)d_in[1];   // hmm_params [U,S,S] f32 (only [0] used)
  int* out = (int*)d_out;                     // states [B,T] int32
  char* ws = (char*)d_ws;

  float* ltc = (float*)(ws + OFF_LTC);
  float* li  = (float*)(ws + OFF_LI);
  float* ltr = (float*)(ws + OFF_LTR);
  float* bnd = (float*)(ws + OFF_BND);
  int*   lst = (int*)(ws + OFF_LAST);
  unsigned char* H  = (unsigned char*)(ws + OFF_H);
  unsigned char* se = (unsigned char*)(ws + OFF_SE);
  unsigned char* bp = (unsigned char*)(ws + OFF_BP);

  k_prep  <<<1,    256, 0, stream>>>(hmm, ltc, li, ltr);
  k_fwd   <<<BB,   64,  0, stream>>>(x, ltr, li, bnd, lst);
  k_chunks<<<1024, 256, 0, stream>>>(x, ltc, bnd, bp, H);
  k_bound <<<1,    256, 0, stream>>>(lst, H, se, out);
  k_fill  <<<1024, 256, 0, stream>>>(bp, se, out);
}

// Round 7
// 1151.714 us; speedup vs baseline: 1.3217x; 1.1367x over previous
//
#include <hip/hip_runtime.h>
#include <math.h>

// Viterbi posterior_mode, bitwise-faithful to the f32 reference:
//   alpha_{t}[j] = max_i(alpha_{t-1}[i] + LT[i][j]) + e_t   (f32, RTNE, first-win argmax)
// K1: sequential alpha-only; the ENTIRE step is one 48-inst inline-asm block
//     (16 v_add + 14 v_max_f32_dpp butterfly + 12-inst permlane16/32 swap-max +
//      2 dpp-mov + 3 cndmask w/ constant SGPR masks + 1 SGPR e-add), hazard-spaced.
// K2: parallel per-chunk recompute with backpointers + fused map composition. K3/K4 backtrack.

#define BB 256
#define TT 8192
#define SS 32
#define LCH 256
#define NCH 32

static constexpr size_t OFF_LTC  = 0;                                    // 32*32 f32 col-major
static constexpr size_t OFF_LI   = 4096;                                 // 32 f32
static constexpr size_t OFF_LTR  = 4224;                                 // 32*32 f32 row-major
static constexpr size_t OFF_BND  = 8448;                                 // NCH*BB*SS f32
static constexpr size_t OFF_LAST = OFF_BND + (size_t)NCH * BB * SS * 4;  // BB i32
static constexpr size_t OFF_H    = OFF_LAST + (size_t)BB * 4;            // NCH*BB*SS u8
static constexpr size_t OFF_SE   = OFF_H + (size_t)NCH * BB * SS;        // NCH*BB u8
static constexpr size_t OFF_BP   = (OFF_SE + (size_t)NCH * BB + 4095) & ~(size_t)4095; // TT*BB*SS u8

static __device__ __forceinline__ float rlane(float v, int i) {
  return __int_as_float(__builtin_amdgcn_readlane(__float_as_int(v), i));
}
// e = (-0.5 * x) * x - HALF_LOG_2PI, exactly as the reference (no FMA contraction)
static __device__ __forceinline__ float emis_f(float x) {
  return __fsub_rn(__fmul_rn(__fmul_rn(-0.5f, x), x), 0.9189385332046727f);
}

// ---- K0: logs (double route -> correctly rounded f32) ----
__global__ void k_prep(const float* __restrict__ hmm, float* __restrict__ ltc,
                       float* __restrict__ li, float* __restrict__ ltr) {
  int tid = threadIdx.x;
  for (int k = tid; k < SS * SS; k += 256) {
    int i = k >> 5, j = k & 31;
    float v = (float)log((double)hmm[i * SS + j]);
    ltc[j * SS + i] = v;   // column-major (k_chunks)
    ltr[i * SS + j] = v;   // row-major (k_fwd)
  }
  if (tid < SS) li[tid] = (float)log((double)hmm[tid]);
}

// One full Viterbi value-step in a single asm block.
// p[s] lives in v(40+s). Butterfly levels: xor2 (quad_perm [2,3,0,1]),
// xor7 (row_half_mirror), xor8 (row_ror:8), xor16 (permlane16_swap),
// xor32 (permlane32_swap). Then 4-way select by lane bits 4/5 (constant masks)
// and the emission add (SGPR src0). Dataflow identical to the round-6 passing kernel.
static __device__ __forceinline__ float fstep(float a, const float* lt, float e,
                                              unsigned long long m4,
                                              unsigned long long m5) {
  float ao;
  asm("v_add_f32 v40, %[A], %[l0]\n\t"
      "v_add_f32 v41, %[A], %[l1]\n\t"
      "v_add_f32 v42, %[A], %[l2]\n\t"
      "v_add_f32 v43, %[A], %[l3]\n\t"
      "v_add_f32 v44, %[A], %[l4]\n\t"
      "v_add_f32 v45, %[A], %[l5]\n\t"
      "v_add_f32 v46, %[A], %[l6]\n\t"
      "v_add_f32 v47, %[A], %[l7]\n\t"
      "v_add_f32 v48, %[A], %[l8]\n\t"
      "v_add_f32 v49, %[A], %[l9]\n\t"
      "v_add_f32 v50, %[A], %[l10]\n\t"
      "v_add_f32 v51, %[A], %[l11]\n\t"
      "v_add_f32 v52, %[A], %[l12]\n\t"
      "v_add_f32 v53, %[A], %[l13]\n\t"
      "v_add_f32 v54, %[A], %[l14]\n\t"
      "v_add_f32 v55, %[A], %[l15]\n\t"
      // L1: p[s] <- max(dpp_xor2(p[s+8]), p[s]), s=0..7
      "v_max_f32_dpp v40, v48, v40 quad_perm:[2,3,0,1] row_mask:0xf bank_mask:0xf\n\t"
      "v_max_f32_dpp v41, v49, v41 quad_perm:[2,3,0,1] row_mask:0xf bank_mask:0xf\n\t"
      "v_max_f32_dpp v42, v50, v42 quad_perm:[2,3,0,1] row_mask:0xf bank_mask:0xf\n\t"
      "v_max_f32_dpp v43, v51, v43 quad_perm:[2,3,0,1] row_mask:0xf bank_mask:0xf\n\t"
      "v_max_f32_dpp v44, v52, v44 quad_perm:[2,3,0,1] row_mask:0xf bank_mask:0xf\n\t"
      "v_max_f32_dpp v45, v53, v45 quad_perm:[2,3,0,1] row_mask:0xf bank_mask:0xf\n\t"
      "v_max_f32_dpp v46, v54, v46 quad_perm:[2,3,0,1] row_mask:0xf bank_mask:0xf\n\t"
      "v_max_f32_dpp v47, v55, v47 quad_perm:[2,3,0,1] row_mask:0xf bank_mask:0xf\n\t"
      // L2: p[s] <- max(dpp_xor7(p[s+4]), p[s]), s=0..3
      "v_max_f32_dpp v40, v44, v40 row_half_mirror row_mask:0xf bank_mask:0xf\n\t"
      "v_max_f32_dpp v41, v45, v41 row_half_mirror row_mask:0xf bank_mask:0xf\n\t"
      "v_max_f32_dpp v42, v46, v42 row_half_mirror row_mask:0xf bank_mask:0xf\n\t"
      "v_max_f32_dpp v43, v47, v43 row_half_mirror row_mask:0xf bank_mask:0xf\n\t"
      // L3: p0 <- max(dpp_xor8(p2), p0); p1 <- max(dpp_xor8(p3), p1)
      "v_max_f32_dpp v40, v42, v40 row_ror:8 row_mask:0xf bank_mask:0xf\n\t"
      "v_max_f32_dpp v41, v43, v41 row_ror:8 row_mask:0xf bank_mask:0xf\n\t"
      // xor16: mov copy, swap, max  (pair {v[l], v[l^16]} under either convention)
      "v_mov_b32 v44, v40\n\t"
      "v_mov_b32 v45, v41\n\t"
      "v_permlane16_swap_b32 v40, v44\n\t"
      "v_permlane16_swap_b32 v41, v45\n\t"
      "v_max_f32 v40, v40, v44\n\t"
      "v_max_f32 v41, v41, v45\n\t"
      // xor32
      "v_mov_b32 v44, v40\n\t"
      "v_mov_b32 v45, v41\n\t"
      "v_permlane32_swap_b32 v40, v44\n\t"
      "v_permlane32_swap_b32 v41, v45\n\t"
      "v_max_f32 v40, v40, v44\n\t"
      "v_max_f32 v41, v41, v45\n\t"
      // xor1 neighbors of the two column-streams
      "v_mov_b32_dpp v46, v40 quad_perm:[1,0,3,2] row_mask:0xf bank_mask:0xf\n\t"
      "v_mov_b32_dpp v47, v41 quad_perm:[1,0,3,2] row_mask:0xf bank_mask:0xf\n\t"
      // select: lo = m5?p1:p0 ; hi = m5?n1:n0 ; v = m4?hi:lo
      "v_cndmask_b32 v42, v40, v41, %[M5]\n\t"
      "v_cndmask_b32 v43, v46, v47, %[M5]\n\t"
      "v_cndmask_b32 v42, v42, v43, %[M4]\n\t"
      // alpha' = v + e  (e in SGPR, src0)
      "v_add_f32 %[AO], %[E], v42"
      : [AO] "=v"(ao)
      : [A] "v"(a), [E] "s"(e), [M4] "s"(m4), [M5] "s"(m5),
        [l0] "v"(lt[0]), [l1] "v"(lt[1]), [l2] "v"(lt[2]), [l3] "v"(lt[3]),
        [l4] "v"(lt[4]), [l5] "v"(lt[5]), [l6] "v"(lt[6]), [l7] "v"(lt[7]),
        [l8] "v"(lt[8]), [l9] "v"(lt[9]), [l10] "v"(lt[10]), [l11] "v"(lt[11]),
        [l12] "v"(lt[12]), [l13] "v"(lt[13]), [l14] "v"(lt[14]), [l15] "v"(lt[15])
      : "v40", "v41", "v42", "v43", "v44", "v45", "v46", "v47", "v48", "v49",
        "v50", "v51", "v52", "v53", "v54", "v55");
  return ao;
}

__global__ __launch_bounds__(64) void k_fwd(const float* __restrict__ x,
                                            const float* __restrict__ ltr,
                                            const float* __restrict__ li,
                                            float* __restrict__ bnd,
                                            int* __restrict__ last) {
  const int b = blockIdx.x, tid = threadIdx.x;
  const int l = tid;
  const int f0 = __popc(l & 5) & 1;
  const int f1 = __popc(l & 6) & 1;
  const int f2 = (l >> 2) & 1;
  const int f3 = (l >> 3) & 1;
  const int sig = ((f0 ^ ((l >> 4) & 1)) << 4) | (f1 << 3) | (f2 << 2) | (f3 << 1) |
                  ((l >> 5) & 1);
  const unsigned long long m4 = 0xFFFF0000FFFF0000ull;  // lane bit4 set
  const unsigned long long m5 = 0xFFFFFFFF00000000ull;  // lane bit5 set
  float lt[16];
#pragma unroll
  for (int r = 0; r < 16; ++r) {
    int j = (f0 << 4) | ((((r >> 3) & 1) ^ f1) << 3) | ((((r >> 2) & 1) ^ f2) << 2) |
            ((((r >> 1) & 1) ^ f3) << 1) | (r & 1);
    lt[r] = ltr[(size_t)sig * SS + j];
  }
  const float* xb = x + (size_t)b * TT;
  const int m = tid & 31;
  float xcur = xb[m];
  float ev = emis_f(xcur);
  float xnxt = xb[32 + m];
  float es[32];
#pragma unroll
  for (int k = 0; k < 32; ++k) es[k] = rlane(ev, k);   // uniform -> SGPRs
  float a = __fadd_rn(li[sig], es[0]);                 // alpha_0
  bnd[(size_t)b * SS + sig] = a;                       // chunk-0 boundary (dup writes ok)
#pragma unroll
  for (int k = 1; k < 32; ++k) a = fstep(a, lt, es[k], m4, m5);
  for (int t0 = 32; t0 < TT; t0 += 32) {
    ev = emis_f(xnxt);
    if (t0 + 32 < TT) xnxt = xb[t0 + 32 + m];
#pragma unroll
    for (int k = 0; k < 32; ++k) es[k] = rlane(ev, k);
    a = fstep(a, lt, es[0], m4, m5);                   // t = t0
    if ((t0 & 255) == 0)
      bnd[((size_t)(t0 >> 8) * BB + b) * SS + sig] = a;
#pragma unroll
    for (int k = 1; k < 32; ++k) a = fstep(a, lt, es[k], m4, m5);
  }
  // last[b] = argmax_j alpha, first (lowest state index) wins
  float mx = a;
#pragma unroll
  for (int o = 1; o < 64; o <<= 1) mx = fmaxf(mx, __shfl_xor(mx, o, 64));
  int v = (a == mx) ? sig : 63;
#pragma unroll
  for (int o = 1; o < 64; o <<= 1) { int u = __shfl_xor(v, o, 64); v = u < v ? u : v; }
  if (tid == 0) last[b] = v;
}

// ---- K2: parallel chunk recompute: backpointers + fused map composition ----
__global__ __launch_bounds__(256) void k_chunks(const float* __restrict__ x,
                                                const float* __restrict__ ltc,
                                                const float* __restrict__ bnd,
                                                unsigned char* __restrict__ bp,
                                                unsigned char* __restrict__ H) {
  __shared__ float alf[8][32];
  __shared__ float els[8][32];
  const int tid = threadIdx.x;
  const int w = tid >> 5, j = tid & 31;
  const int c = blockIdx.x >> 5;
  const int b = ((blockIdx.x & 31) << 3) + w;
  const int tlo = c * LCH;
  const int thi = (tlo + LCH < TT - 1) ? (tlo + LCH) : (TT - 1);
  float lt[32];
  {
    const float4* ltv = (const float4*)(ltc + (size_t)j * SS);
#pragma unroll
    for (int q = 0; q < 8; ++q) {
      float4 v = ltv[q];
      lt[4 * q + 0] = v.x; lt[4 * q + 1] = v.y; lt[4 * q + 2] = v.z; lt[4 * q + 3] = v.w;
    }
  }
  float alpha = bnd[((size_t)c * BB + b) * SS + j];
  int comp = j;  // composed map: end-state -> state at tlo
  const float* xb = x + (size_t)b * TT;

  for (int tg = tlo + 1; tg <= thi; tg += 32) {
    const int kn = (32 < thi - tg + 1) ? 32 : (thi - tg + 1);
    float xv = (j < kn) ? xb[tg + j] : 0.0f;
    els[w][j] = emis_f(xv);   // half-wave private, lockstep -> no barrier
    for (int k = 0; k < kn; ++k) {
      const int t = tg + k;
      alf[w][j] = alpha;
      float sc[32];
      const float4* ap = (const float4*)alf[w];
#pragma unroll
      for (int q = 0; q < 8; ++q) {
        float4 v = ap[q];
        sc[4 * q + 0] = __fadd_rn(v.x, lt[4 * q + 0]);
        sc[4 * q + 1] = __fadd_rn(v.y, lt[4 * q + 1]);
        sc[4 * q + 2] = __fadd_rn(v.z, lt[4 * q + 2]);
        sc[4 * q + 3] = __fadd_rn(v.w, lt[4 * q + 3]);
      }
      // max value (order-free, exact), then first-win index via descending eq-scan
      float mm = sc[0];
#pragma unroll
      for (int i = 1; i < 32; ++i) mm = fmaxf(mm, sc[i]);
      int idx = 31;
#pragma unroll
      for (int i = 30; i >= 0; --i) idx = (sc[i] == mm) ? i : idx;
      alpha = __fadd_rn(mm, els[w][k]);
      bp[(size_t)t * (BB * SS) + (size_t)b * SS + j] = (unsigned char)idx;
      comp = __shfl(comp, idx, 32);  // comp_new[j] = comp_old[bp_t[j]]
    }
  }
  H[((size_t)c * BB + b) * SS + j] = (unsigned char)comp;
}

// ---- K3: boundary backtrack over composed chunk maps (+ states[b][0]) ----
__global__ void k_bound(const int* __restrict__ last, const unsigned char* __restrict__ H,
                        unsigned char* __restrict__ se, int* __restrict__ out) {
  int b = threadIdx.x;  // one block of 256
  int s = last[b];
  for (int c = NCH - 1; c >= 0; --c) {
    se[(size_t)c * BB + b] = (unsigned char)s;      // state at t_hi(c)
    s = H[((size_t)c * BB + b) * SS + s];           // -> state at 256c
  }
  out[(size_t)b * TT] = s;                          // states[b][0]
}

// ---- K4: fill per-chunk paths from bp (LDS-staged walk) ----
__global__ __launch_bounds__(256) void k_fill(const unsigned char* __restrict__ bp,
                                              const unsigned char* __restrict__ se,
                                              int* __restrict__ out) {
  __shared__ unsigned char lbp[8][LCH * SS];  // 64 KiB
  const int tid = threadIdx.x;
  const int w = tid >> 5, j = tid & 31;
  const int c = blockIdx.x >> 5;
  const int b = ((blockIdx.x & 31) << 3) + w;
  const int tlo = c * LCH;
  const int thi = (tlo + LCH < TT - 1) ? (tlo + LCH) : (TT - 1);
  const int n = thi - tlo;
  for (int k = 0; k < n; ++k)
    lbp[w][k * SS + j] = bp[(size_t)(tlo + 1 + k) * (BB * SS) + (size_t)b * SS + j];
  __builtin_amdgcn_wave_barrier();
  if (j == 0) {
    int s = se[(size_t)c * BB + b];                 // state at t_hi
    int* ob = out + (size_t)b * TT;
    for (int k = n - 1; k >= 0; --k) {
      ob[tlo + 1 + k] = s;
      s = lbp[w][k * SS + s];
    }
  }
}

extern "C" void kernel_launch(void* const* d_in, const int* in_sizes, int n_in,
                              void* d_out, int out_size, void* d_ws, size_t ws_size,
                              hipStream_t stream) {
  const float* x   = (const float*)d_in[0];   // inputs [B,T] f32
  const float* hmm = (const float*)d_in[1];   // hmm_params [U,S,S] f32 (only [0] used)
  int* out = (int*)d_out;                     // states [B,T] int32
  char* ws = (char*)d_ws;

  float* ltc = (float*)(ws + OFF_LTC);
  float* li  = (float*)(ws + OFF_LI);
  float* ltr = (float*)(ws + OFF_LTR);
  float* bnd = (float*)(ws + OFF_BND);
  int*   lst = (int*)(ws + OFF_LAST);
  unsigned char* H  = (unsigned char*)(ws + OFF_H);
  unsigned char* se = (unsigned char*)(ws + OFF_SE);
  unsigned char* bp = (unsigned char*)(ws + OFF_BP);

  k_prep  <<<1,    256, 0, stream>>>(hmm, ltc, li, ltr);
  k_fwd   <<<BB,   64,  0, stream>>>(x, ltr, li, bnd, lst);
  k_chunks<<<1024, 256, 0, stream>>>(x, ltc, bnd, bp, H);
  k_bound <<<1,    256, 0, stream>>>(lst, H, se, out);
  k_fill  <<<1024, 256, 0, stream>>>(bp, se, out);
}